// Round 7
// baseline (632.228 us; speedup 1.0000x reference)
//
#include <hip/hip_runtime.h>
#include <stdint.h>

#define NROWS   131072
#define DDIM    256
#define KDIM    768                   // 3 segments x 256
#define BM      256                   // rows per block (8 waves x 32)
#define BN      80                    // gate-cols per block (5 gates x 16 d)
#define NROWT   (NROWS / BM)          // 512 row tiles
#define NCW     16                    // 256/16 d-col tiles
#define NWG     (NROWT * NCW)         // 8192
#define NELEM   ((size_t)NROWS * DDIM)

#define WS_A_BYTES ((size_t)NROWS * KDIM * 2)          // 201,326,592
#define WS_B_OFF   WS_A_BYTES
#define PANEL_B    (BN * KDIM * 2)                     // 122,880 B per cw panel
#define HALF_B     (PANEL_B / 2)                       // 61,440 B
#define WS_B_BYTES ((size_t)NCW * PANEL_B)             // 1,966,080
#define WS_NEEDED  (WS_A_BYTES + WS_B_BYTES)

typedef __attribute__((ext_vector_type(8))) short  vbf16x8;
typedef __attribute__((ext_vector_type(4))) float  vf32x4;
typedef __attribute__((ext_vector_type(4))) unsigned int vu32x4;

__device__ __forceinline__ unsigned pk2(float hi, float lo) {
  return __builtin_amdgcn_perm(__float_as_uint(hi), __float_as_uint(lo), 0x07060302u);
}
__device__ __forceinline__ float sigm(float v)  { return 1.f / (1.f + __expf(-v)); }
__device__ __forceinline__ float tanh_(float v) { return 1.f - 2.f / (1.f + __expf(2.f * v)); }

__device__ __forceinline__ void gload16(const void* g, void* l) {
  __builtin_amdgcn_global_load_lds(
      (const __attribute__((address_space(1))) unsigned int*)g,
      (__attribute__((address_space(3))) unsigned int*)l, 16, 0, 0);
}

// ---- prepass A: x|lh|rh fp32 -> A_ws bf16 [131072][768], PLAIN row-major ----
__global__ __launch_bounds__(256) void prep_a(const float* __restrict__ x,
                                              const float* __restrict__ lh,
                                              const float* __restrict__ rh,
                                              unsigned short* __restrict__ A_ws)
{
  unsigned gid = blockIdx.x * 256u + threadIdx.x;   // < 131072*96
  unsigned r   = gid / 96u;
  unsigned gc  = gid - r * 96u;                     // 8-elem group 0..95
  const float* src = (gc < 32u) ? x : (gc < 64u ? lh : rh);
  const float4* s = (const float4*)(src + (size_t)r * 256u + (gc & 31u) * 8u);
  float4 a0 = s[0], a1 = s[1];
  vu32x4 v = { pk2(a0.y, a0.x), pk2(a0.w, a0.z), pk2(a1.y, a1.x), pk2(a1.w, a1.z) };
  *(vu32x4*)(A_ws + (size_t)r * 768u + gc * 8u) = v;
}

// ---- prepass B: weights -> B_ws bf16 [16 cw][2 half][80 n][384], swizzled ----
// row n: gate=n>>4, dloc=n&15, d=cw*16+dloc. Within each 768B half-row, 16B
// group at kb is stored at kb ^ ((n&7)<<4)  (T2, baked into data).
struct BPrm { const float* w[15]; };                 // [seg 0..2][gate 0..4]
__global__ __launch_bounds__(256) void prep_b(BPrm q, unsigned short* __restrict__ B_ws)
{
  unsigned gid = blockIdx.x * 256u + threadIdx.x;   // < 16*80*96 = 122880
  unsigned cw  = gid / 7680u;
  unsigned rem = gid - cw * 7680u;
  unsigned n   = rem / 96u;
  unsigned gc  = rem - n * 96u;                     // k-group (8 elems)
  unsigned seg  = gc >> 5;
  unsigned gate = n >> 4;
  unsigned dloc = n & 15u;
  const float4* s = (const float4*)(q.w[seg * 5 + gate] +
                     (size_t)(cw * 16u + dloc) * 256u + (gc & 31u) * 8u);
  float4 a0 = s[0], a1 = s[1];
  unsigned half = gc / 48u;                         // k-half (384 elems)
  unsigned kb   = (gc - half * 48u) * 16u;          // byte within half-row
  unsigned kbs  = kb ^ ((n & 7u) << 4);             // T2 swizzle
  vu32x4 v = { pk2(a0.y, a0.x), pk2(a0.w, a0.z), pk2(a1.y, a1.x), pk2(a1.w, a1.z) };
  *(vu32x4*)((char*)B_ws + (size_t)cw * PANEL_B + half * HALF_B + n * 768u + kbs) = v;
}

// ---------------- main GEMM + fused epilogue ----------------
struct GPrm {
  const unsigned short *A, *B;
  const float *lc, *rc, *bcx, *bix, *bfx, *box;
  float* out;
};

// 8 waves x (32 rows x 80 cols). B half-panel (60KB) in LDS, staged twice per
// block (3 barriers TOTAL, none per K-step). A streamed global->regs (each
// byte read once per block; L2-resident panel via XCD remap). acc[2][5]=40
// regs, no staging arrays -> demand ~115 <= 128, (512,4) safe (R4 lesson: the
// spill came from 40 reg-staging VGPRs that no longer exist).
__global__ __launch_bounds__(512, 4) void gemm_fused(GPrm p)
{
  const int t   = threadIdx.x;
  const int bid = blockIdx.x;
  // XCD affinity: j=XCD, 16 consecutive same-XCD blocks share one A panel;
  // all 16 B panels (1.9MB) + ~4 in-flight A panels (1.5MB) fit 4MB L2.
  const int j  = bid & 7;
  const int g  = bid >> 3;
  const int cw = g & 15;
  const int rowBase = ((g >> 4) * 8 + j) * BM;

  __shared__ unsigned short Bs[BN * 384];            // 60 KiB

  const int l  = t & 63;
  const int w  = t >> 6;                             // 0..7
  const int lm = l & 15;
  const int lk = l >> 4;

  // B LDS per-lane bases with swizzle folded in (zero per-read VALU):
  // physical byte = row*768 + [(ks*64 + lk*16) ^ ((lm&7)<<4)]
  //             = (ks even ? Cb : Db)[n] + (ks>>1)*128
  const int xl = (lk ^ (lm & 3)) << 4;
  const int b6 = (lm & 4) << 4;
  int Cb[5], Db[5];
#pragma unroll
  for (int n = 0; n < 5; ++n) {
    const int base = (n * 16 + lm) * 768 + xl;
    Cb[n] = base + b6;
    Db[n] = base + (64 - b6);
  }
  const char* Bc = (const char*)&Bs[0];

  // A fragment stream pointers (row-major [row][768]); k32 step = +64B imm
  const unsigned short* a0p = p.A + (size_t)(rowBase + w * 32 + lm) * 768 + lk * 8;
  const unsigned short* a1p = a0p + 16 * 768;

  vf32x4 acc[2][5];
#pragma unroll
  for (int m = 0; m < 2; ++m)
#pragma unroll
    for (int n = 0; n < 5; ++n) acc[m][n] = (vf32x4)(0.f);

  // stage one 60KB half-panel: 60 x 1KB wave-copies, linear (swizzle in data)
  const unsigned short* bsrc = p.B + ((size_t)cw * PANEL_B) / 2 + (size_t)l * 8;
  auto stageB = [&](int h) {
    const unsigned short* src = bsrc + (h ? HALF_B / 2 : 0);
#pragma unroll
    for (int c = 0; c < 8; ++c) {
      const int q = c * 8 + w;
      if (q < 60) gload16(src + q * 512, &Bs[q * 512]);
    }
  };

  stageB(0);
  __syncthreads();
#pragma unroll
  for (int h = 0; h < 2; ++h) {
    if (h) { __syncthreads(); stageB(1); __syncthreads(); }
#pragma unroll
    for (int tt = 0; tt < 6; ++tt) {
#pragma unroll
      for (int par = 0; par < 2; ++par) {
        const int k32 = h * 12 + tt * 2 + par;
        vbf16x8 af0 = *(const vbf16x8*)(a0p + k32 * 32);
        vbf16x8 af1 = *(const vbf16x8*)(a1p + k32 * 32);
        vbf16x8 bf[5];
#pragma unroll
        for (int n = 0; n < 5; ++n)
          bf[n] = *(const vbf16x8*)(Bc + (par ? Db[n] : Cb[n]) + tt * 128);
        __builtin_amdgcn_s_setprio(1);
#pragma unroll
        for (int n = 0; n < 5; ++n) {
          acc[0][n] = __builtin_amdgcn_mfma_f32_16x16x32_bf16(af0, bf[n], acc[0][n], 0, 0, 0);
          acc[1][n] = __builtin_amdgcn_mfma_f32_16x16x32_bf16(af1, bf[n], acc[1][n], 0, 0, 0);
        }
        __builtin_amdgcn_s_setprio(0);
      }
    }
  }

  // ---- fused epilogue: 5 gates for (row, d) live in acc[m][0..4] ----
  const int dcol = cw * 16 + lm;
  const float bu  = p.bcx[dcol];
  const float bi  = p.bix[dcol];
  const float bff = p.bfx[dcol];
  const float bo  = p.box[dcol];
#pragma unroll
  for (int m = 0; m < 2; ++m) {
    const int r0 = rowBase + w * 32 + m * 16 + lk * 4;
#pragma unroll
    for (int jj = 0; jj < 4; ++jj) {
      const size_t off = (size_t)(r0 + jj) * DDIM + dcol;
      const float pu  = acc[m][0][jj] + bu;
      const float pi  = acc[m][1][jj] + bi;
      const float plf = acc[m][2][jj] + bff;
      const float prf = acc[m][3][jj] + bff;
      const float po  = acc[m][4][jj] + bo;
      const float u  = tanh_(pu);
      const float ig = sigm(pi);
      const float lf = sigm(plf);
      const float rf = sigm(prf);
      const float og = sigm(po);
      const float c  = ig * u + lf * p.lc[off] + rf * p.rc[off];
      const float hh = og * tanh_(c);
      p.out[off]         = c;
      p.out[NELEM + off] = hh;
    }
  }
}

// ---------------- fallback (R3 kernel, used only if ws too small) ----------------
struct Params {
  const float *x, *lh, *rh, *lc, *rc;
  const float *s0g0, *s0g1, *s0g2, *s0g3, *s0g4;
  const float *s1g0, *s1g1, *s1g2, *s1g3, *s1g4;
  const float *s2g0, *s2g1, *s2g2, *s2g3, *s2g4;
  const float *bcx, *bix, *bfx, *box;
  float *out;
};
__global__ __launch_bounds__(256, 2) void fused_tree_cell_fb(Params p)
{
  const int t   = threadIdx.x;
  const int bid = blockIdx.x;
  const int nbid    = (bid & 7) * (NWG / 8) + (bid >> 3);
  const int tileRow = nbid >> 3;
  const int cb      = nbid & 7;
  const int rowBase = tileRow * 128;
  __shared__ short As[128 * 64];
  __shared__ short Bsh[160 * 64];
  const int l  = t & 63;
  const int lm = l & 15;
  const int lk = l >> 4;
  const int w  = t >> 6;
  const int wr = w >> 1;
  const int wc = w & 1;
  vf32x4 acc[4][5];
#pragma unroll
  for (int m = 0; m < 4; ++m)
#pragma unroll
    for (int n = 0; n < 5; ++n) acc[m][n] = (vf32x4)(0.f);
  float4 aR[4][2];
  float4 bR[5][2];
  const int tg  = t >> 3;
  const int kc  = (t & 7) * 8;
  const int kcB = kc * 2;
  auto stage_load = [&](int kt) {
    const int seg  = kt >> 2;
    const int ksub = (kt & 3) * 64;
    const float *ap, *g0, *g1, *g2, *g3, *g4;
    if (seg == 0)      { ap = p.x;  g0 = p.s0g0; g1 = p.s0g1; g2 = p.s0g2; g3 = p.s0g3; g4 = p.s0g4; }
    else if (seg == 1) { ap = p.lh; g0 = p.s1g0; g1 = p.s1g1; g2 = p.s1g2; g3 = p.s1g3; g4 = p.s1g4; }
    else               { ap = p.rh; g0 = p.s2g0; g1 = p.s2g1; g2 = p.s2g2; g3 = p.s2g3; g4 = p.s2g4; }
#pragma unroll
    for (int ps = 0; ps < 4; ++ps) {
      const float* s = ap + (size_t)(rowBase + ps * 32 + tg) * DDIM + ksub + kc;
      aR[ps][0] = *(const float4*)s;
      aR[ps][1] = *(const float4*)(s + 4);
    }
#define BLOAD(ps, GA, GB) { \
    const float* bp = (t & 128) ? (GB) : (GA); \
    const int dloc = ((((ps) * 32) + tg) >= 80 ? 16 : 0) + (tg & 15); \
    const float* s = bp + (size_t)(cb * 32 + dloc) * DDIM + ksub + kc; \
    bR[ps][0] = *(const float4*)s; \
    bR[ps][1] = *(const float4*)(s + 4); }
    BLOAD(0, g0, g1) BLOAD(1, g2, g3) BLOAD(2, g4, g0) BLOAD(3, g1, g2) BLOAD(4, g3, g4)
#undef BLOAD
  };
  auto stage_write = [&]() {
    char* Ab = (char*)&As[0];
#pragma unroll
    for (int ps = 0; ps < 4; ++ps) {
      const int row  = ps * 32 + tg;
      const int byte = (row * 128 + kcB) ^ ((row & 7) << 4);
      vu32x4 v = { pk2(aR[ps][0].y, aR[ps][0].x), pk2(aR[ps][0].w, aR[ps][0].z),
                   pk2(aR[ps][1].y, aR[ps][1].x), pk2(aR[ps][1].w, aR[ps][1].z) };
      *(vu32x4*)(Ab + byte) = v;
    }
    char* Bb = (char*)&Bsh[0];
#pragma unroll
    for (int ps = 0; ps < 5; ++ps) {
      const int row  = ps * 32 + tg;
      const int byte = (row * 128 + kcB) ^ ((row & 7) << 4);
      vu32x4 v = { pk2(bR[ps][0].y, bR[ps][0].x), pk2(bR[ps][0].w, bR[ps][0].z),
                   pk2(bR[ps][1].y, bR[ps][1].x), pk2(bR[ps][1].w, bR[ps][1].z) };
      *(vu32x4*)(Bb + byte) = v;
    }
  };
  auto compute = [&]() {
    const char* Ab = (const char*)&As[0];
    const char* Bb = (const char*)&Bsh[0];
    __builtin_amdgcn_s_setprio(1);
#pragma unroll
    for (int ks = 0; ks < 2; ++ks) {
      vbf16x8 af[4], bf[5];
#pragma unroll
      for (int m = 0; m < 4; ++m) {
        const int row  = wr * 64 + m * 16 + lm;
        const int byte = (row * 128 + ks * 64 + lk * 16) ^ ((row & 7) << 4);
        af[m] = *(const vbf16x8*)(Ab + byte);
      }
#pragma unroll
      for (int n = 0; n < 5; ++n) {
        const int row  = wc * 80 + n * 16 + lm;
        const int byte = (row * 128 + ks * 64 + lk * 16) ^ ((row & 7) << 4);
        bf[n] = *(const vbf16x8*)(Bb + byte);
      }
#pragma unroll
      for (int m = 0; m < 4; ++m)
#pragma unroll
        for (int n = 0; n < 5; ++n)
          acc[m][n] = __builtin_amdgcn_mfma_f32_16x16x32_bf16(af[m], bf[n], acc[m][n], 0, 0, 0);
    }
    __builtin_amdgcn_s_setprio(0);
  };
  stage_load(0);
  stage_write();
  __syncthreads();
  for (int kt = 0; kt < 12; ++kt) {
    if (kt < 11) stage_load(kt + 1);
    compute();
    if (kt < 11) {
      __builtin_amdgcn_sched_barrier(0);
      __builtin_amdgcn_s_barrier();
      stage_write();
      __syncthreads();
    }
  }
  const int dcol = cb * 32 + wc * 16 + lm;
  const float bu  = p.bcx[dcol];
  const float bi  = p.bix[dcol];
  const float bff = p.bfx[dcol];
  const float bo  = p.box[dcol];
#pragma unroll
  for (int m = 0; m < 4; ++m) {
    const int r0 = rowBase + wr * 64 + m * 16 + lk * 4;
#pragma unroll
    for (int jj = 0; jj < 4; ++jj) {
      const size_t off = (size_t)(r0 + jj) * DDIM + dcol;
      const float pu  = acc[m][0][jj] + bu;
      const float pi  = acc[m][1][jj] + bi;
      const float plf = acc[m][2][jj] + bff;
      const float prf = acc[m][3][jj] + bff;
      const float po  = acc[m][4][jj] + bo;
      const float u  = tanh_(pu);
      const float ig = sigm(pi);
      const float lf = sigm(plf);
      const float rf = sigm(prf);
      const float og = sigm(po);
      const float c  = ig * u + lf * p.lc[off] + rf * p.rc[off];
      const float hh = og * tanh_(c);
      p.out[off]         = c;
      p.out[NELEM + off] = hh;
    }
  }
}

extern "C" void kernel_launch(void* const* d_in, const int* in_sizes, int n_in,
                              void* d_out, int out_size, void* d_ws, size_t ws_size,
                              hipStream_t stream)
{
  const float* x  = (const float*)d_in[0];
  const float* lc = (const float*)d_in[1];
  const float* lh = (const float*)d_in[2];
  const float* rc = (const float*)d_in[3];
  const float* rh = (const float*)d_in[4];
  const float* W_cx = (const float*)d_in[5];
  const float* b_cx = (const float*)d_in[6];
  const float* W_ox = (const float*)d_in[7];
  const float* b_ox = (const float*)d_in[8];
  const float* W_fx = (const float*)d_in[9];
  const float* b_fx = (const float*)d_in[10];
  const float* W_ix = (const float*)d_in[11];
  const float* b_ix = (const float*)d_in[12];
  const float* U_ilh  = (const float*)d_in[13];
  const float* U_irh  = (const float*)d_in[14];
  const float* U_lflh = (const float*)d_in[15];
  const float* U_lfrh = (const float*)d_in[16];
  const float* U_rflh = (const float*)d_in[17];
  const float* U_rfrh = (const float*)d_in[18];
  const float* U_ulh  = (const float*)d_in[19];
  const float* U_urh  = (const float*)d_in[20];
  const float* U_olh  = (const float*)d_in[21];
  const float* U_orh  = (const float*)d_in[22];

  if (ws_size >= WS_NEEDED && d_ws != nullptr) {
    unsigned short* A_ws = (unsigned short*)d_ws;
    unsigned short* B_ws = (unsigned short*)((char*)d_ws + WS_B_OFF);
    hipLaunchKernelGGL(prep_a, dim3(NROWS * 96 / 256), dim3(256), 0, stream, x, lh, rh, A_ws);
    BPrm q;
    q.w[0] = W_cx;  q.w[1] = W_ix;  q.w[2] = W_fx;   q.w[3] = W_fx;   q.w[4] = W_ox;
    q.w[5] = U_ulh; q.w[6] = U_ilh; q.w[7] = U_lflh; q.w[8] = U_rflh; q.w[9] = U_olh;
    q.w[10] = U_urh; q.w[11] = U_irh; q.w[12] = U_lfrh; q.w[13] = U_rfrh; q.w[14] = U_orh;
    hipLaunchKernelGGL(prep_b, dim3(16 * 80 * 96 / 256), dim3(256), 0, stream, q, B_ws);
    GPrm g;
    g.A = A_ws; g.B = B_ws; g.lc = lc; g.rc = rc;
    g.bcx = b_cx; g.bix = b_ix; g.bfx = b_fx; g.box = b_ox;
    g.out = (float*)d_out;
    hipLaunchKernelGGL(gemm_fused, dim3(NWG), dim3(512), 0, stream, g);
  } else {
    Params p;
    p.x = x; p.lc = lc; p.lh = lh; p.rc = rc; p.rh = rh;
    p.s0g0 = W_cx;  p.s0g1 = W_ix;  p.s0g2 = W_fx;   p.s0g3 = W_fx;   p.s0g4 = W_ox;
    p.s1g0 = U_ulh; p.s1g1 = U_ilh; p.s1g2 = U_lflh; p.s1g3 = U_rflh; p.s1g4 = U_olh;
    p.s2g0 = U_urh; p.s2g1 = U_irh; p.s2g2 = U_lfrh; p.s2g3 = U_rfrh; p.s2g4 = U_orh;
    p.bcx = b_cx; p.bix = b_ix; p.bfx = b_fx; p.box = b_ox;
    p.out = (float*)d_out;
    hipLaunchKernelGGL(fused_tree_cell_fb, dim3(NWG), dim3(256), 0, stream, p);
  }
}

// Round 8
// 575.799 us; speedup vs baseline: 1.0980x; 1.0980x over previous
//
#include <hip/hip_runtime.h>
#include <stdint.h>

#define NROWS   131072
#define DDIM    256
#define KDIM    768                   // 3 segments x 256
#define BM      128
#define BN      160
#define BK      32
#define NKT     (KDIM / BK)           // 24 K-tiles
#define NWG     8192                  // 1024 row tiles x 8 col tiles
#define NELEM   ((size_t)NROWS * DDIM)

#define WS_A_BYTES ((size_t)NROWS * KDIM * 2)          // 201,326,592
#define WS_B_OFF   WS_A_BYTES
#define WS_B_BYTES ((size_t)8 * BN * KDIM * 2)         // 1,966,080
#define WS_NEEDED  (WS_A_BYTES + WS_B_BYTES)

typedef __attribute__((ext_vector_type(8))) short  vbf16x8;
typedef __attribute__((ext_vector_type(4))) float  vf32x4;
typedef __attribute__((ext_vector_type(4))) unsigned int vu32x4;

__device__ __forceinline__ unsigned pk2(float hi, float lo) {
  return __builtin_amdgcn_perm(__float_as_uint(hi), __float_as_uint(lo), 0x07060302u);
}
__device__ __forceinline__ float sigm(float v)  { return 1.f / (1.f + __expf(-v)); }
__device__ __forceinline__ float tanh_(float v) { return 1.f - 2.f / (1.f + __expf(2.f * v)); }

__device__ __forceinline__ void gload16(const void* g, void* l) {
  __builtin_amdgcn_global_load_lds(
      (const __attribute__((address_space(1))) unsigned int*)g,
      (__attribute__((address_space(3))) unsigned int*)l, 16, 0, 0);
}

// ---- prepass A: x|lh|rh fp32 -> A_ws bf16 [131072][768], PLAIN row-major ----
__global__ __launch_bounds__(256) void prep_a(const float* __restrict__ x,
                                              const float* __restrict__ lh,
                                              const float* __restrict__ rh,
                                              unsigned short* __restrict__ A_ws)
{
  unsigned gid = blockIdx.x * 256u + threadIdx.x;   // < 131072*96
  unsigned r   = gid / 96u;
  unsigned gc  = gid - r * 96u;                     // 8-elem group 0..95
  const float* src = (gc < 32u) ? x : (gc < 64u ? lh : rh);
  const float4* s = (const float4*)(src + (size_t)r * 256u + (gc & 31u) * 8u);
  float4 a0 = s[0], a1 = s[1];
  vu32x4 v = { pk2(a0.y, a0.x), pk2(a0.w, a0.z), pk2(a1.y, a1.x), pk2(a1.w, a1.z) };
  *(vu32x4*)(A_ws + (size_t)r * 768u + gc * 8u) = v;
}

// ---- prepass B: weights -> B_ws bf16 [8 cb][160 n][768], PLAIN row-major ----
// row n (R6-proven order): gate=(n mod 80)>>4, dloc=(n>=80)*16+(n&15), d=cb*32+dloc
struct BPrm { const float* w[15]; };                 // [seg 0..2][gate 0..4]
__global__ __launch_bounds__(256) void prep_b(BPrm q, unsigned short* __restrict__ B_ws)
{
  unsigned gid = blockIdx.x * 256u + threadIdx.x;   // < 8*160*96 = 122880
  unsigned cb  = gid / 15360u;
  unsigned rem = gid - cb * 15360u;
  unsigned n   = rem / 96u;
  unsigned gc  = rem - n * 96u;
  unsigned seg  = gc >> 5;
  unsigned gate = (n >= 80u ? n - 80u : n) >> 4;
  unsigned dloc = (n >= 80u ? 16u : 0u) + (n & 15u);
  const float4* s = (const float4*)(q.w[seg * 5 + gate] +
                     (size_t)(cb * 32u + dloc) * 256u + (gc & 31u) * 8u);
  float4 a0 = s[0], a1 = s[1];
  vu32x4 v = { pk2(a0.y, a0.x), pk2(a0.w, a0.z), pk2(a1.y, a1.x), pk2(a1.w, a1.z) };
  *(vu32x4*)(B_ws + (size_t)(cb * 160u + n) * 768u + gc * 8u) = v;
}

// ---------------- main GEMM + fused epilogue ----------------
struct GPrm {
  const unsigned short *A, *B;
  const float *lc, *rc, *bcx, *bix, *bfx, *box;
  float* out;
};

// T3+T4 port: BK=32, 4 LDS buffers (72 KiB -> 2 blocks/CU), 3-deep prefetch.
// Per iter: waitcnt vmcnt(2m) [tile kt landed, kt+1..kt+3 in flight] -> raw
// s_barrier (NO drain) -> issue(kt+3) -> compute(kt). Loads fly ~3 compute
// phases; vmcnt never hits 0 in steady state. Swizzle: linear LDS dest +
// XOR-pre-swizzled global src + XOR on ds_read (rule 21). 8 waves, acc[2][5].
__global__ __launch_bounds__(512, 4) void gemm_fused(GPrm p)
{
  const int t   = threadIdx.x;
  const int bid = blockIdx.x;
  // XCD A-affinity (R7-proven: FETCH 930->357MB): j=XCD; 8 consecutive
  // same-XCD blocks share one A row-panel (196KB) across all 8 cb.
  const int j   = bid & 7;
  const int g   = bid >> 3;
  const int cb  = g & 7;
  const int rowBase = ((g >> 3) * 8 + j) * BM;

  __shared__ unsigned short As[4][BM * BK];   // 4 x 8 KiB
  __shared__ unsigned short Bs[4][BN * BK];   // 4 x 10 KiB

  const int l  = t & 63;
  const int w  = t >> 6;               // 0..7
  const int lm = l & 15;
  const int lk = l >> 4;
  const int wr = w >> 1;               // 0..3: 32 rows each
  const int wc = w & 1;                // 0..1: 80 cols each

  // staging lanes: lr=row within 16-row call, lg=16B group within 64B row
  const int lr = l >> 2;               // 0..15
  const int lg = l & 3;                // 0..3
  const int sw = (lr >> 1) & 3;        // source-side XOR (involution)

  // per-lane global source bases (XOR swizzle pre-applied to source addr)
  const unsigned short* aSrc = p.A + (size_t)(rowBase + w * 32 + lr) * 768 + (lg ^ sw) * 8;
  const int c0 = (w < 6) ? (w - 4) * 3 : 6 + (w - 6) * 2;   // B call base (w>=4)
  const unsigned short* bSrc = p.B + (size_t)(cb * 160 + c0 * 16 + lr) * 768 + (lg ^ sw) * 8;

  // ds_read per-lane bases; same XOR on read side
  const int xr  = (lk * 16) ^ (((lm >> 1) & 3) << 4);
  const int aRd = (wr * 32 + lm) * 64 + xr;
  const int bRd = (wc * 80 + lm) * 64 + xr;

  vf32x4 acc[2][5];
#pragma unroll
  for (int m = 0; m < 2; ++m)
#pragma unroll
    for (int n = 0; n < 5; ++n) acc[m][n] = (vf32x4)(0.f);

  // issue tile kt: A waves (w<4) 2 calls; B waves: w4,w5 3 calls; w6,w7 2.
  auto issue = [&](int kt) {
    const int buf = kt & 3;
    if (w < 4) {
      const unsigned short* s = aSrc + (size_t)kt * 32;
      unsigned short* l0 = &As[buf][0];
      gload16(s,             l0 + (2 * w) * 512);
      gload16(s + 16 * 768,  l0 + (2 * w + 1) * 512);
    } else {
      const unsigned short* s = bSrc + (size_t)kt * 32;
      unsigned short* l0 = &Bs[buf][0];
      gload16(s,             l0 + c0 * 512);
      gload16(s + 16 * 768,  l0 + (c0 + 1) * 512);
      if (w < 6) gload16(s + 32 * 768, l0 + (c0 + 2) * 512);
    }
  };

  auto compute = [&](int kt) {
    const int buf = kt & 3;
    const char* Ab = (const char*)&As[buf][0];
    const char* Bb = (const char*)&Bs[buf][0];
    vbf16x8 af[2], bf[5];
    af[0] = *(const vbf16x8*)(Ab + aRd);
    af[1] = *(const vbf16x8*)(Ab + aRd + 1024);
#pragma unroll
    for (int n = 0; n < 5; ++n)
      bf[n] = *(const vbf16x8*)(Bb + bRd + n * 1024);
    __builtin_amdgcn_s_setprio(1);
#pragma unroll
    for (int m = 0; m < 2; ++m)
#pragma unroll
      for (int n = 0; n < 5; ++n)
        acc[m][n] = __builtin_amdgcn_mfma_f32_16x16x32_bf16(af[m], bf[n], acc[m][n], 0, 0, 0);
    __builtin_amdgcn_s_setprio(0);
  };

  // prologue: 3 tiles in flight
  issue(0); issue(1); issue(2);

  // steady state kt=0..21: wait vmcnt(2m) -> tile kt done, kt+1.. in flight
  for (int kt = 0; kt < 22; ++kt) {
    if (w == 4 || w == 5) asm volatile("s_waitcnt vmcnt(6)" ::: "memory");
    else                  asm volatile("s_waitcnt vmcnt(4)" ::: "memory");
    __builtin_amdgcn_s_barrier();
    asm volatile("" ::: "memory");
    __builtin_amdgcn_sched_barrier(0);
    if (kt <= 20) issue(kt + 3);
    compute(kt);
  }
  // tail kt=22: only tiles 22,23 outstanding
  if (w == 4 || w == 5) asm volatile("s_waitcnt vmcnt(3)" ::: "memory");
  else                  asm volatile("s_waitcnt vmcnt(2)" ::: "memory");
  __builtin_amdgcn_s_barrier();
  asm volatile("" ::: "memory");
  __builtin_amdgcn_sched_barrier(0);
  compute(22);
  // tail kt=23
  asm volatile("s_waitcnt vmcnt(0)" ::: "memory");
  __builtin_amdgcn_s_barrier();
  asm volatile("" ::: "memory");
  __builtin_amdgcn_sched_barrier(0);
  compute(23);

  // ---- fused epilogue: 5 gates for (row, d) live in acc[m][0..4] ----
  const int dcol = cb * 32 + wc * 16 + lm;
  const float bu  = p.bcx[dcol];
  const float bi  = p.bix[dcol];
  const float bff = p.bfx[dcol];
  const float bo  = p.box[dcol];
#pragma unroll
  for (int m = 0; m < 2; ++m) {
    const int r0 = rowBase + wr * 32 + m * 16 + lk * 4;
#pragma unroll
    for (int jj = 0; jj < 4; ++jj) {
      const size_t off = (size_t)(r0 + jj) * DDIM + dcol;
      const float pu  = acc[m][0][jj] + bu;
      const float pi  = acc[m][1][jj] + bi;
      const float plf = acc[m][2][jj] + bff;
      const float prf = acc[m][3][jj] + bff;
      const float po  = acc[m][4][jj] + bo;
      const float u  = tanh_(pu);
      const float ig = sigm(pi);
      const float lf = sigm(plf);
      const float rf = sigm(prf);
      const float og = sigm(po);
      const float c  = ig * u + lf * p.lc[off] + rf * p.rc[off];
      const float hh = og * tanh_(c);
      p.out[off]         = c;
      p.out[NELEM + off] = hh;
    }
  }
}

// ---------------- fallback (R3 kernel, used only if ws too small) ----------------
struct Params {
  const float *x, *lh, *rh, *lc, *rc;
  const float *s0g0, *s0g1, *s0g2, *s0g3, *s0g4;
  const float *s1g0, *s1g1, *s1g2, *s1g3, *s1g4;
  const float *s2g0, *s2g1, *s2g2, *s2g3, *s2g4;
  const float *bcx, *bix, *bfx, *box;
  float *out;
};
__global__ __launch_bounds__(256, 2) void fused_tree_cell_fb(Params p)
{
  const int t   = threadIdx.x;
  const int bid = blockIdx.x;
  const int nbid    = (bid & 7) * (NWG / 8) + (bid >> 3);
  const int tileRow = nbid >> 3;
  const int cb      = nbid & 7;
  const int rowBase = tileRow * 128;
  __shared__ short Ash[128 * 64];
  __shared__ short Bsh[160 * 64];
  const int l  = t & 63;
  const int lm = l & 15;
  const int lk = l >> 4;
  const int w  = t >> 6;
  const int wr = w >> 1;
  const int wc = w & 1;
  vf32x4 acc[4][5];
#pragma unroll
  for (int m = 0; m < 4; ++m)
#pragma unroll
    for (int n = 0; n < 5; ++n) acc[m][n] = (vf32x4)(0.f);
  float4 aR[4][2];
  float4 bR[5][2];
  const int tg  = t >> 3;
  const int kc  = (t & 7) * 8;
  const int kcB = kc * 2;
  auto stage_load = [&](int kt) {
    const int seg  = kt >> 2;
    const int ksub = (kt & 3) * 64;
    const float *ap, *g0, *g1, *g2, *g3, *g4;
    if (seg == 0)      { ap = p.x;  g0 = p.s0g0; g1 = p.s0g1; g2 = p.s0g2; g3 = p.s0g3; g4 = p.s0g4; }
    else if (seg == 1) { ap = p.lh; g0 = p.s1g0; g1 = p.s1g1; g2 = p.s1g2; g3 = p.s1g3; g4 = p.s1g4; }
    else               { ap = p.rh; g0 = p.s2g0; g1 = p.s2g1; g2 = p.s2g2; g3 = p.s2g3; g4 = p.s2g4; }
#pragma unroll
    for (int ps = 0; ps < 4; ++ps) {
      const float* s = ap + (size_t)(rowBase + ps * 32 + tg) * DDIM + ksub + kc;
      aR[ps][0] = *(const float4*)s;
      aR[ps][1] = *(const float4*)(s + 4);
    }
#define BLOAD(ps, GA, GB) { \
    const float* bp = (t & 128) ? (GB) : (GA); \
    const int dloc = ((((ps) * 32) + tg) >= 80 ? 16 : 0) + (tg & 15); \
    const float* s = bp + (size_t)(cb * 32 + dloc) * DDIM + ksub + kc; \
    bR[ps][0] = *(const float4*)s; \
    bR[ps][1] = *(const float4*)(s + 4); }
    BLOAD(0, g0, g1) BLOAD(1, g2, g3) BLOAD(2, g4, g0) BLOAD(3, g1, g2) BLOAD(4, g3, g4)
#undef BLOAD
  };
  auto stage_write = [&]() {
    char* Ab = (char*)&Ash[0];
#pragma unroll
    for (int ps = 0; ps < 4; ++ps) {
      const int row  = ps * 32 + tg;
      const int byte = (row * 128 + kcB) ^ ((row & 7) << 4);
      vu32x4 v = { pk2(aR[ps][0].y, aR[ps][0].x), pk2(aR[ps][0].w, aR[ps][0].z),
                   pk2(aR[ps][1].y, aR[ps][1].x), pk2(aR[ps][1].w, aR[ps][1].z) };
      *(vu32x4*)(Ab + byte) = v;
    }
    char* Bb = (char*)&Bsh[0];
#pragma unroll
    for (int ps = 0; ps < 5; ++ps) {
      const int row  = ps * 32 + tg;
      const int byte = (row * 128 + kcB) ^ ((row & 7) << 4);
      vu32x4 v = { pk2(bR[ps][0].y, bR[ps][0].x), pk2(bR[ps][0].w, bR[ps][0].z),
                   pk2(bR[ps][1].y, bR[ps][1].x), pk2(bR[ps][1].w, bR[ps][1].z) };
      *(vu32x4*)(Bb + byte) = v;
    }
  };
  auto compute = [&]() {
    const char* Ab = (const char*)&Ash[0];
    const char* Bb = (const char*)&Bsh[0];
#pragma unroll
    for (int ks = 0; ks < 2; ++ks) {
      vbf16x8 af[4], bf[5];
#pragma unroll
      for (int m = 0; m < 4; ++m) {
        const int row  = wr * 64 + m * 16 + lm;
        const int byte = (row * 128 + ks * 64 + lk * 16) ^ ((row & 7) << 4);
        af[m] = *(const vbf16x8*)(Ab + byte);
      }
#pragma unroll
      for (int n = 0; n < 5; ++n) {
        const int row  = wc * 80 + n * 16 + lm;
        const int byte = (row * 128 + ks * 64 + lk * 16) ^ ((row & 7) << 4);
        bf[n] = *(const vbf16x8*)(Bb + byte);
      }
#pragma unroll
      for (int m = 0; m < 4; ++m)
#pragma unroll
        for (int n = 0; n < 5; ++n)
          acc[m][n] = __builtin_amdgcn_mfma_f32_16x16x32_bf16(af[m], bf[n], acc[m][n], 0, 0, 0);
    }
  };
  stage_load(0);
  stage_write();
  __syncthreads();
  for (int kt = 0; kt < 12; ++kt) {
    if (kt < 11) stage_load(kt + 1);
    compute();
    if (kt < 11) {
      __builtin_amdgcn_sched_barrier(0);
      __builtin_amdgcn_s_barrier();
      stage_write();
      __syncthreads();
    }
  }
  const int dcol = cb * 32 + wc * 16 + lm;
  const float bu  = p.bcx[dcol];
  const float bi  = p.bix[dcol];
  const float bff = p.bfx[dcol];
  const float bo  = p.box[dcol];
#pragma unroll
  for (int m = 0; m < 4; ++m) {
    const int r0 = rowBase + wr * 64 + m * 16 + lk * 4;
#pragma unroll
    for (int jj = 0; jj < 4; ++jj) {
      const size_t off = (size_t)(r0 + jj) * DDIM + dcol;
      const float pu  = acc[m][0][jj] + bu;
      const float pi  = acc[m][1][jj] + bi;
      const float plf = acc[m][2][jj] + bff;
      const float prf = acc[m][3][jj] + bff;
      const float po  = acc[m][4][jj] + bo;
      const float u  = tanh_(pu);
      const float ig = sigm(pi);
      const float lf = sigm(plf);
      const float rf = sigm(prf);
      const float og = sigm(po);
      const float c  = ig * u + lf * p.lc[off] + rf * p.rc[off];
      const float hh = og * tanh_(c);
      p.out[off]         = c;
      p.out[NELEM + off] = hh;
    }
  }
}

extern "C" void kernel_launch(void* const* d_in, const int* in_sizes, int n_in,
                              void* d_out, int out_size, void* d_ws, size_t ws_size,
                              hipStream_t stream)
{
  const float* x  = (const float*)d_in[0];
  const float* lc = (const float*)d_in[1];
  const float* lh = (const float*)d_in[2];
  const float* rc = (const float*)d_in[3];
  const float* rh = (const float*)d_in[4];
  const float* W_cx = (const float*)d_in[5];
  const float* b_cx = (const float*)d_in[6];
  const float* W_ox = (const float*)d_in[7];
  const float* b_ox = (const float*)d_in[8];
  const float* W_fx = (const float*)d_in[9];
  const float* b_fx = (const float*)d_in[10];
  const float* W_ix = (const float*)d_in[11];
  const float* b_ix = (const float*)d_in[12];
  const float* U_ilh  = (const float*)d_in[13];
  const float* U_irh  = (const float*)d_in[14];
  const float* U_lflh = (const float*)d_in[15];
  const float* U_lfrh = (const float*)d_in[16];
  const float* U_rflh = (const float*)d_in[17];
  const float* U_rfrh = (const float*)d_in[18];
  const float* U_ulh  = (const float*)d_in[19];
  const float* U_urh  = (const float*)d_in[20];
  const float* U_olh  = (const float*)d_in[21];
  const float* U_orh  = (const float*)d_in[22];

  if (ws_size >= WS_NEEDED && d_ws != nullptr) {
    unsigned short* A_ws = (unsigned short*)d_ws;
    unsigned short* B_ws = (unsigned short*)((char*)d_ws + WS_B_OFF);
    hipLaunchKernelGGL(prep_a, dim3(NROWS * 96 / 256), dim3(256), 0, stream, x, lh, rh, A_ws);
    BPrm q;
    q.w[0] = W_cx;  q.w[1] = W_ix;  q.w[2] = W_fx;   q.w[3] = W_fx;   q.w[4] = W_ox;
    q.w[5] = U_ulh; q.w[6] = U_ilh; q.w[7] = U_lflh; q.w[8] = U_rflh; q.w[9] = U_olh;
    q.w[10] = U_urh; q.w[11] = U_irh; q.w[12] = U_lfrh; q.w[13] = U_rfrh; q.w[14] = U_orh;
    hipLaunchKernelGGL(prep_b, dim3(8 * 160 * 96 / 256), dim3(256), 0, stream, q, B_ws);
    GPrm g;
    g.A = A_ws; g.B = B_ws; g.lc = lc; g.rc = rc;
    g.bcx = b_cx; g.bix = b_ix; g.bfx = b_fx; g.box = b_ox;
    g.out = (float*)d_out;
    hipLaunchKernelGGL(gemm_fused, dim3(NWG), dim3(512), 0, stream, g);
  } else {
    Params p;
    p.x = x; p.lc = lc; p.lh = lh; p.rc = rc; p.rh = rh;
    p.s0g0 = W_cx;  p.s0g1 = W_ix;  p.s0g2 = W_fx;   p.s0g3 = W_fx;   p.s0g4 = W_ox;
    p.s1g0 = U_ulh; p.s1g1 = U_ilh; p.s1g2 = U_lflh; p.s1g3 = U_rflh; p.s1g4 = U_olh;
    p.s2g0 = U_urh; p.s2g1 = U_irh; p.s2g2 = U_lfrh; p.s2g3 = U_rfrh; p.s2g4 = U_orh;
    p.bcx = b_cx; p.bix = b_ix; p.bfx = b_fx; p.box = b_ox;
    p.out = (float*)d_out;
    hipLaunchKernelGGL(fused_tree_cell_fb, dim3(NWG), dim3(256), 0, stream, p);
  }
}

// Round 9
// 517.472 us; speedup vs baseline: 1.2218x; 1.1127x over previous
//
#include <hip/hip_runtime.h>
#include <stdint.h>

#define NROWS   131072
#define DDIM    256
#define KDIM    768                   // 3 segments x 256
#define BM      256
#define BN      160
#define BK      32
#define NKT     (KDIM / BK)           // 24 K-tiles
#define NWG     4096                  // 512 row tiles x 8 col tiles
#define NELEM   ((size_t)NROWS * DDIM)

#define BUFB    26624                 // A 16KB + B 10KB + 384 pad
#define ABYTES  16384
#define WS_A_BYTES ((size_t)NROWS * KDIM * 2)          // 201,326,592
#define WS_B_OFF   WS_A_BYTES
#define WS_B_BYTES ((size_t)8 * BN * KDIM * 2)         // 1,966,080
#define WS_NEEDED  (WS_A_BYTES + WS_B_BYTES)

typedef __attribute__((ext_vector_type(8))) short  vbf16x8;
typedef __attribute__((ext_vector_type(4))) float  vf32x4;
typedef __attribute__((ext_vector_type(4))) unsigned int vu32x4;

__device__ __forceinline__ unsigned pk2(float hi, float lo) {
  return __builtin_amdgcn_perm(__float_as_uint(hi), __float_as_uint(lo), 0x07060302u);
}
__device__ __forceinline__ float sigm(float v)  { return 1.f / (1.f + __expf(-v)); }
__device__ __forceinline__ float tanh_(float v) { return 1.f - 2.f / (1.f + __expf(2.f * v)); }

__device__ __forceinline__ void gload16(const void* g, void* l) {
  __builtin_amdgcn_global_load_lds(
      (const __attribute__((address_space(1))) unsigned int*)g,
      (__attribute__((address_space(3))) unsigned int*)l, 16, 0, 0);
}

// ---- prepass A: x|lh|rh fp32 -> A_ws bf16 [131072][768], PLAIN row-major ----
__global__ __launch_bounds__(256) void prep_a(const float* __restrict__ x,
                                              const float* __restrict__ lh,
                                              const float* __restrict__ rh,
                                              unsigned short* __restrict__ A_ws)
{
  unsigned gid = blockIdx.x * 256u + threadIdx.x;   // < 131072*96
  unsigned r   = gid / 96u;
  unsigned gc  = gid - r * 96u;                     // 8-elem group 0..95
  const float* src = (gc < 32u) ? x : (gc < 64u ? lh : rh);
  const float4* s = (const float4*)(src + (size_t)r * 256u + (gc & 31u) * 8u);
  float4 a0 = s[0], a1 = s[1];
  vu32x4 v = { pk2(a0.y, a0.x), pk2(a0.w, a0.z), pk2(a1.y, a1.x), pk2(a1.w, a1.z) };
  *(vu32x4*)(A_ws + (size_t)r * 768u + gc * 8u) = v;
}

// ---- prepass B: weights -> B_ws bf16 [8 cb][160 n][768], PLAIN row-major ----
// row n: gate=(n mod 80)>>4, dloc=(n>=80)*16+(n&15), d=cb*32+dloc
struct BPrm { const float* w[15]; };                 // [seg 0..2][gate 0..4]
__global__ __launch_bounds__(256) void prep_b(BPrm q, unsigned short* __restrict__ B_ws)
{
  unsigned gid = blockIdx.x * 256u + threadIdx.x;   // < 8*160*96 = 122880
  unsigned cb  = gid / 15360u;
  unsigned rem = gid - cb * 15360u;
  unsigned n   = rem / 96u;
  unsigned gc  = rem - n * 96u;
  unsigned seg  = gc >> 5;
  unsigned gate = (n >= 80u ? n - 80u : n) >> 4;
  unsigned dloc = (n >= 80u ? 16u : 0u) + (n & 15u);
  const float4* s = (const float4*)(q.w[seg * 5 + gate] +
                     (size_t)(cb * 32u + dloc) * 256u + (gc & 31u) * 8u);
  float4 a0 = s[0], a1 = s[1];
  vu32x4 v = { pk2(a0.y, a0.x), pk2(a0.w, a0.z), pk2(a1.y, a1.x), pk2(a1.w, a1.z) };
  *(vu32x4*)(B_ws + (size_t)(cb * 160u + n) * 768u + gc * 8u) = v;
}

// ---------------- main GEMM + fused epilogue ----------------
struct GPrm {
  const unsigned short *A, *B;
  const float *lc, *rc, *bcx, *bix, *bfx, *box;
  float* out;
};

// acc[8][5]: wave = 128 rows x 80 cols -> 332 B LDS-read per MFMA (vs R6/R8's
// 717) — halves the LDS operand-feed pressure that capped MfmaUtil at ~25%.
// 4 waves, BM=256, BN=160, BK=32, 3 LDS buffers (78KB -> 2 blocks/CU),
// depth-2 counted vmcnt (never drains in steady state), raw barriers.
// Register math: acc 160 + frags ~24 + addr ~35 ≈ 220 <= 256 -> (256,2) safe.
__global__ __launch_bounds__(256, 2) void gemm_fused(GPrm p)
{
  const int t   = threadIdx.x;
  const int bid = blockIdx.x;
  // XCD A-affinity: j=XCD; 8 consecutive same-XCD blocks share one A panel.
  const int j   = bid & 7;
  const int g   = bid >> 3;
  const int cb  = g & 7;
  const int rowBase = ((g >> 3) * 8 + j) * BM;

  __shared__ char Lds[3 * BUFB];      // 3 x (A 16KB | B 10KB | pad)

  const int l  = t & 63;
  const int w  = t >> 6;               // 0..3
  const int lm = l & 15;
  const int lk = l >> 4;
  const int wr = w >> 1;               // 0..1: 128 rows each
  const int wc = w & 1;                // 0..1: 80 cols each

  // staging lanes: 1KB/wave-call = 16 rows x 4 groups of 16B
  const int lr = l >> 2;               // 0..15 row within call
  const int lg = l & 3;                // 0..3  16B group
  const int sw = (lr >> 1) & 3;        // source-side XOR (involution, R8-proven)

  // per-lane global source bases (XOR pre-applied to source address)
  const unsigned short* aSrc = p.A + (size_t)(rowBase + w * 128 + lr) * 768 + (lg ^ sw) * 8;
  const unsigned short* bSrc = p.B + (size_t)(cb * 160 + (w - 2) * 80 + lr) * 768 + (lg ^ sw) * 8;

  // ds_read per-lane base offsets; same XOR on read side
  const int xr  = (lk ^ ((lm >> 1) & 3)) << 4;
  const int aRd = (wr * 128 + lm) * 64 + xr;            // + m*1024
  const int bRd = ABYTES + (wc * 80 + lm) * 64 + xr;    // + n*1024

  vf32x4 acc[8][5];
#pragma unroll
  for (int m = 0; m < 8; ++m)
#pragma unroll
    for (int n = 0; n < 5; ++n) acc[m][n] = (vf32x4)(0.f);

  // issue tile kt into buffer bo: A waves (w<2) 8 calls, B waves 5 calls
  auto issue = [&](int kt, int bo) {
    if (w < 2) {
      const unsigned short* s = aSrc + (size_t)kt * 32;
      char* l0 = &Lds[bo] + w * 8192;
#pragma unroll
      for (int c = 0; c < 8; ++c)
        gload16(s + (size_t)c * 16 * 768, l0 + c * 1024);
    } else {
      const unsigned short* s = bSrc + (size_t)kt * 32;
      char* l0 = &Lds[bo] + ABYTES + (w - 2) * 5120;
#pragma unroll
      for (int c = 0; c < 5; ++c)
        gload16(s + (size_t)c * 16 * 768, l0 + c * 1024);
    }
  };

  auto compute = [&](int bo) {
    const char* L = &Lds[0];
    const int aB = bo + aRd;
    const int bB = bo + bRd;
    vbf16x8 bf[5];
#pragma unroll
    for (int n = 0; n < 5; ++n)
      bf[n] = *(const vbf16x8*)(L + bB + n * 1024);
    __builtin_amdgcn_s_setprio(1);
#pragma unroll
    for (int m = 0; m < 8; ++m) {
      vbf16x8 af = *(const vbf16x8*)(L + aB + m * 1024);
#pragma unroll
      for (int n = 0; n < 5; ++n)
        acc[m][n] = __builtin_amdgcn_mfma_f32_16x16x32_bf16(af, bf[n], acc[m][n], 0, 0, 0);
    }
    __builtin_amdgcn_s_setprio(0);
  };

  // prologue: 2 tiles in flight (depth-2)
  issue(0, 0);
  issue(1, BUFB);

#pragma unroll
  for (int kt = 0; kt < NKT; ++kt) {
    // wait own loads of tile kt (tile kt+1 stays in flight); NEVER drain to 0
    if (kt < NKT - 1) {
      if (w < 2) asm volatile("s_waitcnt vmcnt(8)" ::: "memory");
      else       asm volatile("s_waitcnt vmcnt(5)" ::: "memory");
    } else {
      asm volatile("s_waitcnt vmcnt(0)" ::: "memory");
    }
    __builtin_amdgcn_s_barrier();      // all waves' tile-kt loads now complete
    __builtin_amdgcn_sched_barrier(0);
    if (kt < NKT - 2) issue(kt + 2, ((kt + 2) % 3) * BUFB);  // overwrites kt-1's buf (readers done)
    compute((kt % 3) * BUFB);
  }

  // ---- fused epilogue: 5 gates for (row, d) live in acc[m][0..4] ----
  const int dcol = cb * 32 + wc * 16 + lm;
  const float bu  = p.bcx[dcol];
  const float bi  = p.bix[dcol];
  const float bff = p.bfx[dcol];
  const float bo_ = p.box[dcol];
#pragma unroll
  for (int m = 0; m < 8; ++m) {
    const int r0 = rowBase + wr * 128 + m * 16 + lk * 4;
#pragma unroll
    for (int jj = 0; jj < 4; ++jj) {
      const size_t off = (size_t)(r0 + jj) * DDIM + dcol;
      const float pu  = acc[m][0][jj] + bu;
      const float pi  = acc[m][1][jj] + bi;
      const float plf = acc[m][2][jj] + bff;
      const float prf = acc[m][3][jj] + bff;
      const float po  = acc[m][4][jj] + bo_;
      const float u  = tanh_(pu);
      const float ig = sigm(pi);
      const float lf = sigm(plf);
      const float rf = sigm(prf);
      const float og = sigm(po);
      const float c  = ig * u + lf * p.lc[off] + rf * p.rc[off];
      const float hh = og * tanh_(c);
      p.out[off]         = c;
      p.out[NELEM + off] = hh;
    }
  }
}

// ---------------- fallback (R3 kernel, used only if ws too small) ----------------
struct Params {
  const float *x, *lh, *rh, *lc, *rc;
  const float *s0g0, *s0g1, *s0g2, *s0g3, *s0g4;
  const float *s1g0, *s1g1, *s1g2, *s1g3, *s1g4;
  const float *s2g0, *s2g1, *s2g2, *s2g3, *s2g4;
  const float *bcx, *bix, *bfx, *box;
  float *out;
};
__global__ __launch_bounds__(256, 2) void fused_tree_cell_fb(Params p)
{
  const int t   = threadIdx.x;
  const int bid = blockIdx.x;
  const int nbid    = (bid & 7) * 1024 + (bid >> 3);
  const int tileRow = nbid >> 3;
  const int cb      = nbid & 7;
  const int rowBase = tileRow * 128;
  __shared__ short Ash[128 * 64];
  __shared__ short Bsh[160 * 64];
  const int l  = t & 63;
  const int lm = l & 15;
  const int lk = l >> 4;
  const int w  = t >> 6;
  const int wr = w >> 1;
  const int wc = w & 1;
  vf32x4 acc[4][5];
#pragma unroll
  for (int m = 0; m < 4; ++m)
#pragma unroll
    for (int n = 0; n < 5; ++n) acc[m][n] = (vf32x4)(0.f);
  float4 aR[4][2];
  float4 bR[5][2];
  const int tg  = t >> 3;
  const int kc  = (t & 7) * 8;
  const int kcB = kc * 2;
  auto stage_load = [&](int kt) {
    const int seg  = kt >> 2;
    const int ksub = (kt & 3) * 64;
    const float *ap, *g0, *g1, *g2, *g3, *g4;
    if (seg == 0)      { ap = p.x;  g0 = p.s0g0; g1 = p.s0g1; g2 = p.s0g2; g3 = p.s0g3; g4 = p.s0g4; }
    else if (seg == 1) { ap = p.lh; g0 = p.s1g0; g1 = p.s1g1; g2 = p.s1g2; g3 = p.s1g3; g4 = p.s1g4; }
    else               { ap = p.rh; g0 = p.s2g0; g1 = p.s2g1; g2 = p.s2g2; g3 = p.s2g3; g4 = p.s2g4; }
#pragma unroll
    for (int ps = 0; ps < 4; ++ps) {
      const float* s = ap + (size_t)(rowBase + ps * 32 + tg) * DDIM + ksub + kc;
      aR[ps][0] = *(const float4*)s;
      aR[ps][1] = *(const float4*)(s + 4);
    }
#define BLOAD(ps, GA, GB) { \
    const float* bp = (t & 128) ? (GB) : (GA); \
    const int dloc = ((((ps) * 32) + tg) >= 80 ? 16 : 0) + (tg & 15); \
    const float* s = bp + (size_t)(cb * 32 + dloc) * DDIM + ksub + kc; \
    bR[ps][0] = *(const float4*)s; \
    bR[ps][1] = *(const float4*)(s + 4); }
    BLOAD(0, g0, g1) BLOAD(1, g2, g3) BLOAD(2, g4, g0) BLOAD(3, g1, g2) BLOAD(4, g3, g4)
#undef BLOAD
  };
  auto stage_write = [&]() {
    char* Ab = (char*)&Ash[0];
#pragma unroll
    for (int ps = 0; ps < 4; ++ps) {
      const int row  = ps * 32 + tg;
      const int byte = (row * 128 + kcB) ^ ((row & 7) << 4);
      vu32x4 v = { pk2(aR[ps][0].y, aR[ps][0].x), pk2(aR[ps][0].w, aR[ps][0].z),
                   pk2(aR[ps][1].y, aR[ps][1].x), pk2(aR[ps][1].w, aR[ps][1].z) };
      *(vu32x4*)(Ab + byte) = v;
    }
    char* Bb = (char*)&Bsh[0];
#pragma unroll
    for (int ps = 0; ps < 5; ++ps) {
      const int row  = ps * 32 + tg;
      const int byte = (row * 128 + kcB) ^ ((row & 7) << 4);
      vu32x4 v = { pk2(bR[ps][0].y, bR[ps][0].x), pk2(bR[ps][0].w, bR[ps][0].z),
                   pk2(bR[ps][1].y, bR[ps][1].x), pk2(bR[ps][1].w, bR[ps][1].z) };
      *(vu32x4*)(Bb + byte) = v;
    }
  };
  auto compute = [&]() {
    const char* Ab = (const char*)&Ash[0];
    const char* Bb = (const char*)&Bsh[0];
#pragma unroll
    for (int ks = 0; ks < 2; ++ks) {
      vbf16x8 af[4], bf[5];
#pragma unroll
      for (int m = 0; m < 4; ++m) {
        const int row  = wr * 64 + m * 16 + lm;
        const int byte = (row * 128 + ks * 64 + lk * 16) ^ ((row & 7) << 4);
        af[m] = *(const vbf16x8*)(Ab + byte);
      }
#pragma unroll
      for (int n = 0; n < 5; ++n) {
        const int row  = wc * 80 + n * 16 + lm;
        const int byte = (row * 128 + ks * 64 + lk * 16) ^ ((row & 7) << 4);
        bf[n] = *(const vbf16x8*)(Bb + byte);
      }
#pragma unroll
      for (int m = 0; m < 4; ++m)
#pragma unroll
        for (int n = 0; n < 5; ++n)
          acc[m][n] = __builtin_amdgcn_mfma_f32_16x16x32_bf16(af[m], bf[n], acc[m][n], 0, 0, 0);
    }
  };
  stage_load(0);
  stage_write();
  __syncthreads();
  for (int kt = 0; kt < 12; ++kt) {
    if (kt < 11) stage_load(kt + 1);
    compute();
    if (kt < 11) {
      __builtin_amdgcn_sched_barrier(0);
      __builtin_amdgcn_s_barrier();
      stage_write();
      __syncthreads();
    }
  }
  const int dcol = cb * 32 + wc * 16 + lm;
  const float bu  = p.bcx[dcol];
  const float bi  = p.bix[dcol];
  const float bff = p.bfx[dcol];
  const float bo  = p.box[dcol];
#pragma unroll
  for (int m = 0; m < 4; ++m) {
    const int r0 = rowBase + wr * 64 + m * 16 + lk * 4;
#pragma unroll
    for (int jj = 0; jj < 4; ++jj) {
      const size_t off = (size_t)(r0 + jj) * DDIM + dcol;
      const float pu  = acc[m][0][jj] + bu;
      const float pi  = acc[m][1][jj] + bi;
      const float plf = acc[m][2][jj] + bff;
      const float prf = acc[m][3][jj] + bff;
      const float po  = acc[m][4][jj] + bo;
      const float u  = tanh_(pu);
      const float ig = sigm(pi);
      const float lf = sigm(plf);
      const float rf = sigm(prf);
      const float og = sigm(po);
      const float c  = ig * u + lf * p.lc[off] + rf * p.rc[off];
      const float hh = og * tanh_(c);
      p.out[off]         = c;
      p.out[NELEM + off] = hh;
    }
  }
}

extern "C" void kernel_launch(void* const* d_in, const int* in_sizes, int n_in,
                              void* d_out, int out_size, void* d_ws, size_t ws_size,
                              hipStream_t stream)
{
  const float* x  = (const float*)d_in[0];
  const float* lc = (const float*)d_in[1];
  const float* lh = (const float*)d_in[2];
  const float* rc = (const float*)d_in[3];
  const float* rh = (const float*)d_in[4];
  const float* W_cx = (const float*)d_in[5];
  const float* b_cx = (const float*)d_in[6];
  const float* W_ox = (const float*)d_in[7];
  const float* b_ox = (const float*)d_in[8];
  const float* W_fx = (const float*)d_in[9];
  const float* b_fx = (const float*)d_in[10];
  const float* W_ix = (const float*)d_in[11];
  const float* b_ix = (const float*)d_in[12];
  const float* U_ilh  = (const float*)d_in[13];
  const float* U_irh  = (const float*)d_in[14];
  const float* U_lflh = (const float*)d_in[15];
  const float* U_lfrh = (const float*)d_in[16];
  const float* U_rflh = (const float*)d_in[17];
  const float* U_rfrh = (const float*)d_in[18];
  const float* U_ulh  = (const float*)d_in[19];
  const float* U_urh  = (const float*)d_in[20];
  const float* U_olh  = (const float*)d_in[21];
  const float* U_orh  = (const float*)d_in[22];

  if (ws_size >= WS_NEEDED && d_ws != nullptr) {
    unsigned short* A_ws = (unsigned short*)d_ws;
    unsigned short* B_ws = (unsigned short*)((char*)d_ws + WS_B_OFF);
    hipLaunchKernelGGL(prep_a, dim3(NROWS * 96 / 256), dim3(256), 0, stream, x, lh, rh, A_ws);
    BPrm q;
    q.w[0] = W_cx;  q.w[1] = W_ix;  q.w[2] = W_fx;   q.w[3] = W_fx;   q.w[4] = W_ox;
    q.w[5] = U_ulh; q.w[6] = U_ilh; q.w[7] = U_lflh; q.w[8] = U_rflh; q.w[9] = U_olh;
    q.w[10] = U_urh; q.w[11] = U_irh; q.w[12] = U_lfrh; q.w[13] = U_rfrh; q.w[14] = U_orh;
    hipLaunchKernelGGL(prep_b, dim3(8 * 160 * 96 / 256), dim3(256), 0, stream, q, B_ws);
    GPrm g;
    g.A = A_ws; g.B = B_ws; g.lc = lc; g.rc = rc;
    g.bcx = b_cx; g.bix = b_ix; g.bfx = b_fx; g.box = b_ox;
    g.out = (float*)d_out;
    hipLaunchKernelGGL(gemm_fused, dim3(NWG), dim3(256), 0, stream, g);
  } else {
    Params p;
    p.x = x; p.lc = lc; p.lh = lh; p.rc = rc; p.rh = rh;
    p.s0g0 = W_cx;  p.s0g1 = W_ix;  p.s0g2 = W_fx;   p.s0g3 = W_fx;   p.s0g4 = W_ox;
    p.s1g0 = U_ulh; p.s1g1 = U_ilh; p.s1g2 = U_lflh; p.s1g3 = U_rflh; p.s1g4 = U_olh;
    p.s2g0 = U_urh; p.s2g1 = U_irh; p.s2g2 = U_lfrh; p.s2g3 = U_rfrh; p.s2g4 = U_orh;
    p.bcx = b_cx; p.bix = b_ix; p.bfx = b_fx; p.box = b_ox;
    p.out = (float*)d_out;
    hipLaunchKernelGGL(fused_tree_cell_fb, dim3(8192), dim3(256), 0, stream, p);
  }
}

// Round 10
// 506.933 us; speedup vs baseline: 1.2472x; 1.0208x over previous
//
#include <hip/hip_runtime.h>
#include <stdint.h>

#define NROWS   131072
#define DDIM    256
#define KDIM    768                   // 3 segments x 256
#define BM      128
#define BN      160
#define BK      32
#define NKT     (KDIM / BK)           // 24 K-tiles
#define NWG     8192                  // 1024 row tiles x 8 col tiles
#define NELEM   ((size_t)NROWS * DDIM)

#define ABYTES  8192                  // A tile 128x32x2
#define BUFB    18432                 // + B tile 160x32x2 = 10240
#define WS_A_BYTES ((size_t)NROWS * KDIM * 2)          // 201,326,592
#define WS_B_OFF   WS_A_BYTES
#define WS_B_BYTES ((size_t)8 * BN * KDIM * 2)         // 1,966,080
#define WS_NEEDED  (WS_A_BYTES + WS_B_BYTES)

typedef __attribute__((ext_vector_type(8))) short  vbf16x8;
typedef __attribute__((ext_vector_type(4))) float  vf32x4;
typedef __attribute__((ext_vector_type(4))) unsigned int vu32x4;

__device__ __forceinline__ unsigned pk2(float hi, float lo) {
  return __builtin_amdgcn_perm(__float_as_uint(hi), __float_as_uint(lo), 0x07060302u);
}
__device__ __forceinline__ float sigm(float v)  { return 1.f / (1.f + __expf(-v)); }
__device__ __forceinline__ float tanh_(float v) { return 1.f - 2.f / (1.f + __expf(2.f * v)); }

__device__ __forceinline__ void gload16(const void* g, void* l) {
  __builtin_amdgcn_global_load_lds(
      (const __attribute__((address_space(1))) unsigned int*)g,
      (__attribute__((address_space(3))) unsigned int*)l, 16, 0, 0);
}

// ---- prepass A: x|lh|rh fp32 -> A_ws bf16 [131072][768], PLAIN row-major ----
__global__ __launch_bounds__(256) void prep_a(const float* __restrict__ x,
                                              const float* __restrict__ lh,
                                              const float* __restrict__ rh,
                                              unsigned short* __restrict__ A_ws)
{
  unsigned gid = blockIdx.x * 256u + threadIdx.x;   // < 131072*96
  unsigned r   = gid / 96u;
  unsigned gc  = gid - r * 96u;                     // 8-elem group 0..95
  const float* src = (gc < 32u) ? x : (gc < 64u ? lh : rh);
  const float4* s = (const float4*)(src + (size_t)r * 256u + (gc & 31u) * 8u);
  float4 a0 = s[0], a1 = s[1];
  vu32x4 v = { pk2(a0.y, a0.x), pk2(a0.w, a0.z), pk2(a1.y, a1.x), pk2(a1.w, a1.z) };
  *(vu32x4*)(A_ws + (size_t)r * 768u + gc * 8u) = v;
}

// ---- prepass B: weights -> B_ws bf16 [8 cb][160 n][768], PLAIN row-major ----
// row n: gate=(n mod 80)>>4, dloc=(n>=80)*16+(n&15), d=cb*32+dloc
struct BPrm { const float* w[15]; };                 // [seg 0..2][gate 0..4]
__global__ __launch_bounds__(256) void prep_b(BPrm q, unsigned short* __restrict__ B_ws)
{
  unsigned gid = blockIdx.x * 256u + threadIdx.x;   // < 8*160*96 = 122880
  unsigned cb  = gid / 15360u;
  unsigned rem = gid - cb * 15360u;
  unsigned n   = rem / 96u;
  unsigned gc  = rem - n * 96u;
  unsigned seg  = gc >> 5;
  unsigned gate = (n >= 80u ? n - 80u : n) >> 4;
  unsigned dloc = (n >= 80u ? 16u : 0u) + (n & 15u);
  const float4* s = (const float4*)(q.w[seg * 5 + gate] +
                     (size_t)(cb * 32u + dloc) * 256u + (gc & 31u) * 8u);
  float4 a0 = s[0], a1 = s[1];
  vu32x4 v = { pk2(a0.y, a0.x), pk2(a0.w, a0.z), pk2(a1.y, a1.x), pk2(a1.w, a1.z) };
  *(vu32x4*)(B_ws + (size_t)(cb * 160u + n) * 768u + gc * 8u) = v;
}

// ---------------- main GEMM + fused epilogue ----------------
struct GPrm {
  const unsigned short *A, *B;
  const float *lc, *rc, *bcx, *bix, *bfx, *box;
  float* out;
};

// Synthesis of R6 (occupancy works, reuse too low: LDS-fabric-bound) and
// R9 (reuse works, occupancy too low: latency-bound):
// 256 thr / 4 waves, wave tile 64x80 -> acc[4][5]=80 acc regs (450 B LDS-read
// per MFMA). BK=32, 2 x 18KB LDS buffers. Regs ~135 -> launch_bounds(256,3)
// (cap 170 >> demand, no R2/R4 spill mode) -> 3 blocks/CU = 12 waves/CU;
// 3 independent block phases hide the per-step drain (m97 mechanism).
__global__ __launch_bounds__(256, 3) void gemm_fused(GPrm p)
{
  const int t   = threadIdx.x;
  const int bid = blockIdx.x;
  // XCD A-affinity (R7-proven): j=XCD; 8 consecutive same-XCD blocks share
  // one 196KB A row-panel across all 8 cb -> A HBM-fetched ~once.
  const int j   = bid & 7;
  const int g   = bid >> 3;
  const int cb  = g & 7;
  const int rowBase = ((g >> 3) * 8 + j) * BM;

  __shared__ char Lds[2 * BUFB];       // 2 x (A 8KB | B 10KB)

  const int l  = t & 63;
  const int w  = t >> 6;               // 0..3
  const int lm = l & 15;
  const int lk = l >> 4;
  const int wr = w >> 1;               // 0..1: 64 rows each
  const int wc = w & 1;                // 0..1: 80 cols each

  // staging lanes: 1KB/wave-call = 16 rows x 4 x 16B (R9's proven layout)
  const int lr = l >> 2;               // 0..15 row within call
  const int lg = l & 3;                // 0..3  16B group
  const int sw = (lr >> 1) & 3;        // source-side XOR (0-conflict, R8/R9)

  // per-lane global source bases (XOR pre-applied to source address)
  const unsigned short* aSrc = p.A + (size_t)(rowBase + w * 64 + lr) * 768 + (lg ^ sw) * 8;
  const unsigned short* bSrc = p.B + (size_t)(cb * 160 + (w - 2) * 80 + lr) * 768 + (lg ^ sw) * 8;

  // ds_read per-lane base offsets; same XOR on read side (0 conflicts, R9)
  const int xr  = (lk ^ ((lm >> 1) & 3)) << 4;
  const int aRd = (wr * 64 + lm) * 64 + xr;             // + m*1024
  const int bRd = ABYTES + (wc * 80 + lm) * 64 + xr;    // + n*1024

  vf32x4 acc[4][5];
#pragma unroll
  for (int m = 0; m < 4; ++m)
#pragma unroll
    for (int n = 0; n < 5; ++n) acc[m][n] = (vf32x4)(0.f);

  // issue tile kt: A waves (w<2) 4 calls, B waves (w>=2) 5 calls
  auto issue = [&](int kt, int bo) {
    if (w < 2) {
      const unsigned short* s = aSrc + (size_t)kt * 32;
      char* l0 = &Lds[bo] + w * 4096;
#pragma unroll
      for (int c = 0; c < 4; ++c)
        gload16(s + (size_t)c * 16 * 768, l0 + c * 1024);
    } else {
      const unsigned short* s = bSrc + (size_t)kt * 32;
      char* l0 = &Lds[bo] + ABYTES + (w - 2) * 5120;
#pragma unroll
      for (int c = 0; c < 5; ++c)
        gload16(s + (size_t)c * 16 * 768, l0 + c * 1024);
    }
  };

  auto compute = [&](int bo) {
    const char* L = &Lds[0];
    const int aB = bo + aRd;
    const int bB = bo + bRd;
    vbf16x8 bf[5];
#pragma unroll
    for (int n = 0; n < 5; ++n)
      bf[n] = *(const vbf16x8*)(L + bB + n * 1024);
    __builtin_amdgcn_s_setprio(1);
#pragma unroll
    for (int m = 0; m < 4; ++m) {
      vbf16x8 af = *(const vbf16x8*)(L + aB + m * 1024);
#pragma unroll
      for (int n = 0; n < 5; ++n)
        acc[m][n] = __builtin_amdgcn_mfma_f32_16x16x32_bf16(af, bf[n], acc[m][n], 0, 0, 0);
    }
    __builtin_amdgcn_s_setprio(0);
  };

  // R6-proven 2-phase: sync drains tile kt (flew during compute(kt-1));
  // issue kt+1 immediately after -> it flies during compute(kt). 3 blocks/CU
  // at independent phases hide each other's drain stalls.
  issue(0, 0);
#pragma unroll 2
  for (int kt = 0; kt < NKT; ++kt) {
    __syncthreads();
    if (kt < NKT - 1) issue(kt + 1, ((kt + 1) & 1) * BUFB);
    compute((kt & 1) * BUFB);
  }

  // ---- fused epilogue: 5 gates for (row, d) live in acc[m][0..4] ----
  const int dcol = cb * 32 + wc * 16 + lm;
  const float bu  = p.bcx[dcol];
  const float bi  = p.bix[dcol];
  const float bff = p.bfx[dcol];
  const float bo_ = p.box[dcol];
#pragma unroll
  for (int m = 0; m < 4; ++m) {
    const int r0 = rowBase + wr * 64 + m * 16 + lk * 4;
#pragma unroll
    for (int jj = 0; jj < 4; ++jj) {
      const size_t off = (size_t)(r0 + jj) * DDIM + dcol;
      const float pu  = acc[m][0][jj] + bu;
      const float pi  = acc[m][1][jj] + bi;
      const float plf = acc[m][2][jj] + bff;
      const float prf = acc[m][3][jj] + bff;
      const float po  = acc[m][4][jj] + bo_;
      const float u  = tanh_(pu);
      const float ig = sigm(pi);
      const float lf = sigm(plf);
      const float rf = sigm(prf);
      const float og = sigm(po);
      const float c  = ig * u + lf * p.lc[off] + rf * p.rc[off];
      const float hh = og * tanh_(c);
      p.out[off]         = c;
      p.out[NELEM + off] = hh;
    }
  }
}

// ---------------- fallback (R3 kernel, used only if ws too small) ----------------
struct Params {
  const float *x, *lh, *rh, *lc, *rc;
  const float *s0g0, *s0g1, *s0g2, *s0g3, *s0g4;
  const float *s1g0, *s1g1, *s1g2, *s1g3, *s1g4;
  const float *s2g0, *s2g1, *s2g2, *s2g3, *s2g4;
  const float *bcx, *bix, *bfx, *box;
  float *out;
};
__global__ __launch_bounds__(256, 2) void fused_tree_cell_fb(Params p)
{
  const int t   = threadIdx.x;
  const int bid = blockIdx.x;
  const int nbid    = (bid & 7) * 1024 + (bid >> 3);
  const int tileRow = nbid >> 3;
  const int cb      = nbid & 7;
  const int rowBase = tileRow * 128;
  __shared__ short Ash[128 * 64];
  __shared__ short Bsh[160 * 64];
  const int l  = t & 63;
  const int lm = l & 15;
  const int lk = l >> 4;
  const int w  = t >> 6;
  const int wr = w >> 1;
  const int wc = w & 1;
  vf32x4 acc[4][5];
#pragma unroll
  for (int m = 0; m < 4; ++m)
#pragma unroll
    for (int n = 0; n < 5; ++n) acc[m][n] = (vf32x4)(0.f);
  float4 aR[4][2];
  float4 bR[5][2];
  const int tg  = t >> 3;
  const int kc  = (t & 7) * 8;
  const int kcB = kc * 2;
  auto stage_load = [&](int kt) {
    const int seg  = kt >> 2;
    const int ksub = (kt & 3) * 64;
    const float *ap, *g0, *g1, *g2, *g3, *g4;
    if (seg == 0)      { ap = p.x;  g0 = p.s0g0; g1 = p.s0g1; g2 = p.s0g2; g3 = p.s0g3; g4 = p.s0g4; }
    else if (seg == 1) { ap = p.lh; g0 = p.s1g0; g1 = p.s1g1; g2 = p.s1g2; g3 = p.s1g3; g4 = p.s1g4; }
    else               { ap = p.rh; g0 = p.s2g0; g1 = p.s2g1; g2 = p.s2g2; g3 = p.s2g3; g4 = p.s2g4; }
#pragma unroll
    for (int ps = 0; ps < 4; ++ps) {
      const float* s = ap + (size_t)(rowBase + ps * 32 + tg) * DDIM + ksub + kc;
      aR[ps][0] = *(const float4*)s;
      aR[ps][1] = *(const float4*)(s + 4);
    }
#define BLOAD(ps, GA, GB) { \
    const float* bp = (t & 128) ? (GB) : (GA); \
    const int dloc = ((((ps) * 32) + tg) >= 80 ? 16 : 0) + (tg & 15); \
    const float* s = bp + (size_t)(cb * 32 + dloc) * DDIM + ksub + kc; \
    bR[ps][0] = *(const float4*)s; \
    bR[ps][1] = *(const float4*)(s + 4); }
    BLOAD(0, g0, g1) BLOAD(1, g2, g3) BLOAD(2, g4, g0) BLOAD(3, g1, g2) BLOAD(4, g3, g4)
#undef BLOAD
  };
  auto stage_write = [&]() {
    char* Ab = (char*)&Ash[0];
#pragma unroll
    for (int ps = 0; ps < 4; ++ps) {
      const int row  = ps * 32 + tg;
      const int byte = (row * 128 + kcB) ^ ((row & 7) << 4);
      vu32x4 v = { pk2(aR[ps][0].y, aR[ps][0].x), pk2(aR[ps][0].w, aR[ps][0].z),
                   pk2(aR[ps][1].y, aR[ps][1].x), pk2(aR[ps][1].w, aR[ps][1].z) };
      *(vu32x4*)(Ab + byte) = v;
    }
    char* Bb = (char*)&Bsh[0];
#pragma unroll
    for (int ps = 0; ps < 5; ++ps) {
      const int row  = ps * 32 + tg;
      const int byte = (row * 128 + kcB) ^ ((row & 7) << 4);
      vu32x4 v = { pk2(bR[ps][0].y, bR[ps][0].x), pk2(bR[ps][0].w, bR[ps][0].z),
                   pk2(bR[ps][1].y, bR[ps][1].x), pk2(bR[ps][1].w, bR[ps][1].z) };
      *(vu32x4*)(Bb + byte) = v;
    }
  };
  auto compute = [&]() {
    const char* Ab = (const char*)&Ash[0];
    const char* Bb = (const char*)&Bsh[0];
#pragma unroll
    for (int ks = 0; ks < 2; ++ks) {
      vbf16x8 af[4], bf[5];
#pragma unroll
      for (int m = 0; m < 4; ++m) {
        const int row  = wr * 64 + m * 16 + lm;
        const int byte = (row * 128 + ks * 64 + lk * 16) ^ ((row & 7) << 4);
        af[m] = *(const vbf16x8*)(Ab + byte);
      }
#pragma unroll
      for (int n = 0; n < 5; ++n) {
        const int row  = wc * 80 + n * 16 + lm;
        const int byte = (row * 128 + ks * 64 + lk * 16) ^ ((row & 7) << 4);
        bf[n] = *(const vbf16x8*)(Bb + byte);
      }
#pragma unroll
      for (int m = 0; m < 4; ++m)
#pragma unroll
        for (int n = 0; n < 5; ++n)
          acc[m][n] = __builtin_amdgcn_mfma_f32_16x16x32_bf16(af[m], bf[n], acc[m][n], 0, 0, 0);
    }
  };
  stage_load(0);
  stage_write();
  __syncthreads();
  for (int kt = 0; kt < 12; ++kt) {
    if (kt < 11) stage_load(kt + 1);
    compute();
    if (kt < 11) {
      __builtin_amdgcn_sched_barrier(0);
      __builtin_amdgcn_s_barrier();
      stage_write();
      __syncthreads();
    }
  }
  const int dcol = cb * 32 + wc * 16 + lm;
  const float bu  = p.bcx[dcol];
  const float bi  = p.bix[dcol];
  const float bff = p.bfx[dcol];
  const float bo  = p.box[dcol];
#pragma unroll
  for (int m = 0; m < 4; ++m) {
    const int r0 = rowBase + wr * 64 + m * 16 + lk * 4;
#pragma unroll
    for (int jj = 0; jj < 4; ++jj) {
      const size_t off = (size_t)(r0 + jj) * DDIM + dcol;
      const float pu  = acc[m][0][jj] + bu;
      const float pi  = acc[m][1][jj] + bi;
      const float plf = acc[m][2][jj] + bff;
      const float prf = acc[m][3][jj] + bff;
      const float po  = acc[m][4][jj] + bo;
      const float u  = tanh_(pu);
      const float ig = sigm(pi);
      const float lf = sigm(plf);
      const float rf = sigm(prf);
      const float og = sigm(po);
      const float c  = ig * u + lf * p.lc[off] + rf * p.rc[off];
      const float hh = og * tanh_(c);
      p.out[off]         = c;
      p.out[NELEM + off] = hh;
    }
  }
}

extern "C" void kernel_launch(void* const* d_in, const int* in_sizes, int n_in,
                              void* d_out, int out_size, void* d_ws, size_t ws_size,
                              hipStream_t stream)
{
  const float* x  = (const float*)d_in[0];
  const float* lc = (const float*)d_in[1];
  const float* lh = (const float*)d_in[2];
  const float* rc = (const float*)d_in[3];
  const float* rh = (const float*)d_in[4];
  const float* W_cx = (const float*)d_in[5];
  const float* b_cx = (const float*)d_in[6];
  const float* W_ox = (const float*)d_in[7];
  const float* b_ox = (const float*)d_in[8];
  const float* W_fx = (const float*)d_in[9];
  const float* b_fx = (const float*)d_in[10];
  const float* W_ix = (const float*)d_in[11];
  const float* b_ix = (const float*)d_in[12];
  const float* U_ilh  = (const float*)d_in[13];
  const float* U_irh  = (const float*)d_in[14];
  const float* U_lflh = (const float*)d_in[15];
  const float* U_lfrh = (const float*)d_in[16];
  const float* U_rflh = (const float*)d_in[17];
  const float* U_rfrh = (const float*)d_in[18];
  const float* U_ulh  = (const float*)d_in[19];
  const float* U_urh  = (const float*)d_in[20];
  const float* U_olh  = (const float*)d_in[21];
  const float* U_orh  = (const float*)d_in[22];

  if (ws_size >= WS_NEEDED && d_ws != nullptr) {
    unsigned short* A_ws = (unsigned short*)d_ws;
    unsigned short* B_ws = (unsigned short*)((char*)d_ws + WS_B_OFF);
    hipLaunchKernelGGL(prep_a, dim3(NROWS * 96 / 256), dim3(256), 0, stream, x, lh, rh, A_ws);
    BPrm q;
    q.w[0] = W_cx;  q.w[1] = W_ix;  q.w[2] = W_fx;   q.w[3] = W_fx;   q.w[4] = W_ox;
    q.w[5] = U_ulh; q.w[6] = U_ilh; q.w[7] = U_lflh; q.w[8] = U_rflh; q.w[9] = U_olh;
    q.w[10] = U_urh; q.w[11] = U_irh; q.w[12] = U_lfrh; q.w[13] = U_rfrh; q.w[14] = U_orh;
    hipLaunchKernelGGL(prep_b, dim3(8 * 160 * 96 / 256), dim3(256), 0, stream, q, B_ws);
    GPrm g;
    g.A = A_ws; g.B = B_ws; g.lc = lc; g.rc = rc;
    g.bcx = b_cx; g.bix = b_ix; g.bfx = b_fx; g.box = b_ox;
    g.out = (float*)d_out;
    hipLaunchKernelGGL(gemm_fused, dim3(NWG), dim3(256), 0, stream, g);
  } else {
    Params p;
    p.x = x; p.lc = lc; p.lh = lh; p.rc = rc; p.rh = rh;
    p.s0g0 = W_cx;  p.s0g1 = W_ix;  p.s0g2 = W_fx;   p.s0g3 = W_fx;   p.s0g4 = W_ox;
    p.s1g0 = U_ulh; p.s1g1 = U_ilh; p.s1g2 = U_lflh; p.s1g3 = U_rflh; p.s1g4 = U_olh;
    p.s2g0 = U_urh; p.s2g1 = U_irh; p.s2g2 = U_lfrh; p.s2g3 = U_rfrh; p.s2g4 = U_orh;
    p.bcx = b_cx; p.bix = b_ix; p.bfx = b_fx; p.box = b_ox;
    p.out = (float*)d_out;
    hipLaunchKernelGGL(fused_tree_cell_fb, dim3(8192), dim3(256), 0, stream, p);
  }
}